// Round 8
// baseline (85.312 us; speedup 1.0000x reference)
//
#include <hip/hip_runtime.h>
#include <math.h>

#define NN 20000
#define NE 640000
#define FDIM 8
#define PDIM 12
#define HDIM 32
#define FP 96            // FDIM * PDIM
#define CAP 80           // per-node bucket capacity; max degree ~57 for Poisson(32)

typedef _Float16 half4v __attribute__((ext_vector_type(4)));
typedef _Float16 half8v __attribute__((ext_vector_type(8)));

// ---- prep: zero cursors, x -> fp16 table, fold weights, softmax (no edge deps) ----
__global__ __launch_bounds__(256) void k_prep(
        const float* __restrict__ x,
        int* __restrict__ cursor, _Float16* __restrict__ xh,
        const float* __restrict__ Wz, const float* __restrict__ bz,
        const float* __restrict__ Wh, const float* __restrict__ bh,
        const float* __restrict__ Lz, const float* __restrict__ lbz,
        const float* __restrict__ Lh, const float* __restrict__ lbh,
        const float* __restrict__ att,
        float* __restrict__ Mz, float* __restrict__ Mh,
        float* __restrict__ cz, float* __restrict__ ch,
        float* __restrict__ probs) {
    int tid = blockIdx.x * 256 + threadIdx.x;

    if (tid < NN / 4) reinterpret_cast<int4*>(cursor)[tid] = make_int4(0, 0, 0, 0);

    if (tid < NN * (FP / 8)) {
        const float4* xp = reinterpret_cast<const float4*>(x) + (size_t)tid * 2;
        float4 a = xp[0], b = xp[1];
        half8v h;
        h[0] = (_Float16)a.x; h[1] = (_Float16)a.y;
        h[2] = (_Float16)a.z; h[3] = (_Float16)a.w;
        h[4] = (_Float16)b.x; h[5] = (_Float16)b.y;
        h[6] = (_Float16)b.z; h[7] = (_Float16)b.w;
        reinterpret_cast<half8v*>(xh)[tid] = h;
    }

    // ---- block 0: fold Mz = Wz @ Lz_top, cz = bz @ Lz_top + lbz; softmax(att) ----
    if (blockIdx.x == 0) {
        int t = threadIdx.x;
        int f = t >> 5, h = t & 31;               // 256 threads = 8x32 exactly
        float mz = 0.f, mh = 0.f;
        for (int k = 0; k < HDIM; ++k) {
            mz += Wz[f * HDIM + k] * Lz[k * HDIM + h];
            mh += Wh[f * HDIM + k] * Lh[k * HDIM + h];
        }
        Mz[f * HDIM + h] = mz;
        Mh[f * HDIM + h] = mh;
        if (f == 0) {
            float a = lbz[h], b2 = lbh[h];
            for (int k = 0; k < HDIM; ++k) {
                a  += bz[k] * Lz[k * HDIM + h];
                b2 += bh[k] * Lh[k * HDIM + h];
            }
            cz[h] = a; ch[h] = b2;
        }
        if (t == 0) {
            float m = -1e30f;
            for (int p = 0; p < PDIM; ++p) m = fmaxf(m, att[p]);
            float e[PDIM]; float ss = 0.f;
            for (int p = 0; p < PDIM; ++p) { e[p] = expf(att[p] - m); ss += e[p]; }
            for (int p = 0; p < PDIM; ++p) probs[p] = e[p] / ss;
        }
    }
}

// ---------------- bucket edges by dst: 4 edges/thread via int4 ----------------
__global__ __launch_bounds__(256) void k_bucket(
        const int* __restrict__ src, const int* __restrict__ dst,
        int* __restrict__ cursor, int* __restrict__ ebuf) {
    int i = blockIdx.x * 256 + threadIdx.x;      // grid covers NE/4 exactly
    int4 d4 = reinterpret_cast<const int4*>(dst)[i];
    int4 s4 = reinterpret_cast<const int4*>(src)[i];
    int p0 = atomicAdd(&cursor[d4.x], 1);
    if (p0 < CAP) ebuf[d4.x * CAP + p0] = s4.x;
    int p1 = atomicAdd(&cursor[d4.y], 1);
    if (p1 < CAP) ebuf[d4.y * CAP + p1] = s4.y;
    int p2 = atomicAdd(&cursor[d4.z], 1);
    if (p2 < CAP) ebuf[d4.z * CAP + p2] = s4.z;
    int p3 = atomicAdd(&cursor[d4.w], 1);
    if (p3 < CAP) ebuf[d4.w * CAP + p3] = s4.w;
}

// ---------------- fused gather + per-node compute ----------------
// block = 256 threads = 8 nodes x 32 lanes (gather: lanes<24, half4/lane; compute: lane=h)
__global__ __launch_bounds__(256) void k_gnode(
        const _Float16* __restrict__ xh, const int* __restrict__ cursor,
        const int* __restrict__ ebuf,
        const float* __restrict__ Mz, const float* __restrict__ Mh,
        const float* __restrict__ cz, const float* __restrict__ ch,
        const float* __restrict__ probs,
        const float* __restrict__ linW, const float* __restrict__ linb,
        float* __restrict__ out) {
    __shared__ float4 sx4[8 * 24];    // 8 nodes x 96 floats (aggregated)
    __shared__ float sh[8][HDIM];
    __shared__ float sprobs[PDIM];

    int tid  = threadIdx.x;
    int li   = tid >> 5;
    int lane = tid & 31;
    int node = blockIdx.x * 8 + li;   // NN = 8*2500 exactly

    if (tid < PDIM) sprobs[tid] = probs[tid];

    if (lane < 24) {
        int cn = cursor[node];
        float dd = rsqrtf((float)cn + 1.0f);
        int e1 = cn < CAP ? cn : CAP;
        const half4v* xh4 = reinterpret_cast<const half4v*>(xh);
        half4v hs = xh4[node * 24 + lane];
        // self-loop: dd * x[node]; final scale by dd gives dd^2 * x[node]
        float ax = dd * (float)hs[0], ay = dd * (float)hs[1];
        float az = dd * (float)hs[2], aw = dd * (float)hs[3];
        const int* eb = ebuf + node * CAP;
        int j = 0;
        for (; j + 4 <= e1; j += 4) {
            int s0 = eb[j], s1 = eb[j + 1], s2 = eb[j + 2], s3 = eb[j + 3];
            float w0 = rsqrtf((float)cursor[s0] + 1.0f);
            float w1 = rsqrtf((float)cursor[s1] + 1.0f);
            float w2 = rsqrtf((float)cursor[s2] + 1.0f);
            float w3 = rsqrtf((float)cursor[s3] + 1.0f);
            half4v a0 = xh4[s0 * 24 + lane], a1 = xh4[s1 * 24 + lane];
            half4v a2 = xh4[s2 * 24 + lane], a3 = xh4[s3 * 24 + lane];
            ax += w0 * (float)a0[0] + w1 * (float)a1[0] + w2 * (float)a2[0] + w3 * (float)a3[0];
            ay += w0 * (float)a0[1] + w1 * (float)a1[1] + w2 * (float)a2[1] + w3 * (float)a3[1];
            az += w0 * (float)a0[2] + w1 * (float)a1[2] + w2 * (float)a2[2] + w3 * (float)a3[2];
            aw += w0 * (float)a0[3] + w1 * (float)a1[3] + w2 * (float)a2[3] + w3 * (float)a3[3];
        }
        for (; j < e1; ++j) {
            int s = eb[j];
            float wq = rsqrtf((float)cursor[s] + 1.0f);
            half4v a = xh4[s * 24 + lane];
            ax += wq * (float)a[0]; ay += wq * (float)a[1];
            az += wq * (float)a[2]; aw += wq * (float)a[3];
        }
        float4 o;
        o.x = dd * ax; o.y = dd * ay; o.z = dd * az; o.w = dd * aw;
        sx4[li * 24 + lane] = o;
    }
    __syncthreads();

    // per-(node, h) compute with folded weights; h = lane
    int h = lane;
    float rMz[FDIM], rMh[FDIM];
#pragma unroll
    for (int f = 0; f < FDIM; ++f) {
        rMz[f] = Mz[f * HDIM + h];
        rMh[f] = Mh[f * HDIM + h];
    }
    float u[PDIM], v[PDIM];
    float c0 = cz[h], c1 = ch[h];
#pragma unroll
    for (int t = 0; t < PDIM; ++t) { u[t] = c0; v[t] = c1; }

    const float* sxf = reinterpret_cast<const float*>(&sx4[li * 24]);
#pragma unroll
    for (int f = 0; f < FDIM; ++f) {
        const float4 a = *reinterpret_cast<const float4*>(sxf + f * PDIM);
        const float4 b = *reinterpret_cast<const float4*>(sxf + f * PDIM + 4);
        const float4 c = *reinterpret_cast<const float4*>(sxf + f * PDIM + 8);
        float mz = rMz[f], mh = rMh[f];
        u[0] += a.x * mz; u[1]  += a.y * mz; u[2]  += a.z * mz; u[3]  += a.w * mz;
        u[4] += b.x * mz; u[5]  += b.y * mz; u[6]  += b.z * mz; u[7]  += b.w * mz;
        u[8] += c.x * mz; u[9]  += c.y * mz; u[10] += c.z * mz; u[11] += c.w * mz;
        v[0] += a.x * mh; v[1]  += a.y * mh; v[2]  += a.z * mh; v[3]  += a.w * mh;
        v[4] += b.x * mh; v[5]  += b.y * mh; v[6]  += b.z * mh; v[7]  += b.w * mh;
        v[8] += c.x * mh; v[9]  += c.y * mh; v[10] += c.z * mh; v[11] += c.w * mh;
    }

    float accum = 0.f;
#pragma unroll
    for (int t = 0; t < PDIM; ++t) {
        float omz = 1.f / (1.f + __expf(u[t]));             // 1 - sigmoid(u)
        float th  = 1.f - 2.f / (__expf(2.f * v[t]) + 1.f); // tanh(v), overflow-safe
        accum += sprobs[t] * omz * th;
    }
    sh[li][h] = fmaxf(accum, 0.f);
    __builtin_amdgcn_wave_barrier();   // producers/consumers share the wave

    if (h < PDIM) {
        float o = linb[h];
#pragma unroll
        for (int k = 0; k < HDIM; ++k) o += sh[li][k] * linW[k * PDIM + h];
        out[(size_t)node * PDIM + h] = o;
    }
}

static inline size_t al256(size_t x) { return (x + 255) & ~(size_t)255; }

extern "C" void kernel_launch(void* const* d_in, const int* in_sizes, int n_in,
                              void* d_out, int out_size, void* d_ws, size_t ws_size,
                              hipStream_t stream) {
    const float* x    = (const float*)d_in[0];
    const int*   ei   = (const int*)d_in[1];
    const float* Wz   = (const float*)d_in[2];
    const float* bz   = (const float*)d_in[3];
    // d_in[4..5] (W_r, b_r) dead: H=0 kills the R gate
    const float* Wh   = (const float*)d_in[6];
    const float* bh   = (const float*)d_in[7];
    const float* Lz   = (const float*)d_in[8];
    const float* lbz  = (const float*)d_in[9];
    // d_in[10..11] (L_r, lb_r) dead
    const float* Lh   = (const float*)d_in[12];
    const float* lbh  = (const float*)d_in[13];
    const float* att  = (const float*)d_in[14];
    const float* linW = (const float*)d_in[15];
    const float* linb = (const float*)d_in[16];
    float* out = (float*)d_out;

    const int* src = ei;
    const int* dst = ei + NE;

    char* w = (char*)d_ws;
    size_t o = 0;
    int*      cursor = (int*)(w + o);      o += al256((size_t)NN * 4);
    int*      ebuf   = (int*)(w + o);      o += al256((size_t)NN * CAP * 4);   // 6.4 MB
    _Float16* xh     = (_Float16*)(w + o); o += al256((size_t)NN * FP * 2);    // 3.84 MB
    float*    Mz     = (float*)(w + o);    o += al256((size_t)FDIM * HDIM * 4);
    float*    Mh     = (float*)(w + o);    o += al256((size_t)FDIM * HDIM * 4);
    float*    czp    = (float*)(w + o);    o += al256((size_t)HDIM * 4);
    float*    chp    = (float*)(w + o);    o += al256((size_t)HDIM * 4);
    float*    probs  = (float*)(w + o);    o += al256((size_t)PDIM * 4);

    const int B = 256;
    k_prep<<<(NN * (FP / 8) + B - 1) / B, B, 0, stream>>>(x, cursor, xh,
                                                          Wz, bz, Wh, bh,
                                                          Lz, lbz, Lh, lbh, att,
                                                          Mz, Mh, czp, chp, probs);
    k_bucket<<<NE / 4 / B, B, 0, stream>>>(src, dst, cursor, ebuf);
    k_gnode<<<NN / 8, B, 0, stream>>>(xh, cursor, ebuf,
                                      Mz, Mh, czp, chp, probs, linW, linb, out);
}

// Round 9
// 74.576 us; speedup vs baseline: 1.1440x; 1.1440x over previous
//
#include <hip/hip_runtime.h>
#include <math.h>

#define NN 20000
#define NE 640000
#define FDIM 8
#define PDIM 12
#define HDIM 32
#define FP 96            // FDIM * PDIM
#define CAP 80           // per-node bucket capacity; max degree ~57 for Poisson(32)
#define CSTR 16          // cursor stride in ints (64B) to cut per-line atomic contention

typedef _Float16 half4v __attribute__((ext_vector_type(4)));
typedef _Float16 half8v __attribute__((ext_vector_type(8)));

// ---- prep: zero strided cursors + fold weights + softmax (all edge-independent) ----
__global__ __launch_bounds__(256) void k_prep(
        int* __restrict__ cursor,
        const float* __restrict__ Wz, const float* __restrict__ bz,
        const float* __restrict__ Wh, const float* __restrict__ bh,
        const float* __restrict__ Lz, const float* __restrict__ lbz,
        const float* __restrict__ Lh, const float* __restrict__ lbh,
        const float* __restrict__ att,
        float* __restrict__ Mz, float* __restrict__ Mh,
        float* __restrict__ cz, float* __restrict__ ch,
        float* __restrict__ probs) {
    int tid = blockIdx.x * 256 + threadIdx.x;
    if (tid < NN * CSTR / 4) reinterpret_cast<int4*>(cursor)[tid] = make_int4(0, 0, 0, 0);

    if (blockIdx.x == 0) {
        int t = threadIdx.x;
        int f = t >> 5, h = t & 31;               // 256 threads = 8x32 exactly
        float mz = 0.f, mh = 0.f;
        for (int k = 0; k < HDIM; ++k) {
            mz += Wz[f * HDIM + k] * Lz[k * HDIM + h];
            mh += Wh[f * HDIM + k] * Lh[k * HDIM + h];
        }
        Mz[f * HDIM + h] = mz;
        Mh[f * HDIM + h] = mh;
        if (f == 0) {
            float a = lbz[h], b2 = lbh[h];
            for (int k = 0; k < HDIM; ++k) {
                a  += bz[k] * Lz[k * HDIM + h];
                b2 += bh[k] * Lh[k * HDIM + h];
            }
            cz[h] = a; ch[h] = b2;
        }
        if (t == 0) {
            float m = -1e30f;
            for (int p = 0; p < PDIM; ++p) m = fmaxf(m, att[p]);
            float e[PDIM]; float ss = 0.f;
            for (int p = 0; p < PDIM; ++p) { e[p] = expf(att[p] - m); ss += e[p]; }
            for (int p = 0; p < PDIM; ++p) probs[p] = e[p] / ss;
        }
    }
}

// ---------------- bucket edges by dst: 2 edges/thread, strided counters ----------------
__global__ __launch_bounds__(256) void k_bucket(
        const int* __restrict__ src, const int* __restrict__ dst,
        int* __restrict__ cursor, int* __restrict__ ebuf) {
    int i = blockIdx.x * 256 + threadIdx.x;      // grid covers NE/2 exactly
    int2 d2 = reinterpret_cast<const int2*>(dst)[i];
    int2 s2 = reinterpret_cast<const int2*>(src)[i];
    int p0 = atomicAdd(&cursor[d2.x * CSTR], 1);
    if (p0 < CAP) ebuf[d2.x * CAP + p0] = s2.x;
    int p1 = atomicAdd(&cursor[d2.y * CSTR], 1);
    if (p1 < CAP) ebuf[d2.y * CAP + p1] = s2.y;
}

// ------- premultiplied fp16 feature table: xh[n][c] = dinv[n] * x[n][c] -------
__global__ __launch_bounds__(256) void k_xh(const float* __restrict__ x,
                                            const int* __restrict__ cursor,
                                            half8v* __restrict__ xh) {
    int idx = blockIdx.x * 256 + threadIdx.x;   // [0, NN*12): 8 elems each
    if (idx >= NN * (FP / 8)) return;
    int node = idx / (FP / 8);
    float dd = rsqrtf((float)cursor[node * CSTR] + 1.0f);
    const float4* xp = reinterpret_cast<const float4*>(x) + (size_t)idx * 2;
    float4 a = xp[0], b = xp[1];
    half8v h;
    h[0] = (_Float16)(dd * a.x); h[1] = (_Float16)(dd * a.y);
    h[2] = (_Float16)(dd * a.z); h[3] = (_Float16)(dd * a.w);
    h[4] = (_Float16)(dd * b.x); h[5] = (_Float16)(dd * b.y);
    h[6] = (_Float16)(dd * b.z); h[7] = (_Float16)(dd * b.w);
    xh[idx] = h;
}

// ---------------- fused gather + per-node compute ----------------
// block = 256 threads = 8 nodes x 32 lanes; edge lists staged in LDS first
__global__ __launch_bounds__(256) void k_gnode(
        const _Float16* __restrict__ xh, const int* __restrict__ cursor,
        const int* __restrict__ ebuf,
        const float* __restrict__ Mz, const float* __restrict__ Mh,
        const float* __restrict__ cz, const float* __restrict__ ch,
        const float* __restrict__ probs,
        const float* __restrict__ linW, const float* __restrict__ linb,
        float* __restrict__ out) {
    __shared__ float4 sx4[8 * 24];    // 8 nodes x 96 floats (aggregated)
    __shared__ float sh[8][HDIM];
    __shared__ float sprobs[PDIM];
    __shared__ int   sle[8 * CAP];    // staged edge lists
    __shared__ int   scnt[8];
    __shared__ float sdd[8];

    int tid  = threadIdx.x;
    int node0 = blockIdx.x * 8;       // NN = 8*2500 exactly

    if (tid < PDIM) sprobs[tid] = probs[tid];
    // coalesced staging of this block's edge lists (over-reads past count are unused)
    for (int i = tid; i < 8 * CAP; i += 256) sle[i] = ebuf[(size_t)node0 * CAP + i];
    if (tid < 8) {
        int c = cursor[(node0 + tid) * CSTR];
        scnt[tid] = c < CAP ? c : CAP;
        sdd[tid]  = rsqrtf((float)c + 1.0f);
    }
    __syncthreads();

    int li   = tid >> 5;
    int lane = tid & 31;
    int node = node0 + li;

    if (lane < 24) {
        float dd = sdd[li];
        int e1 = scnt[li];
        const half4v* xh4 = reinterpret_cast<const half4v*>(xh);
        half4v hs = xh4[node * 24 + lane];        // = dd * x[node] (premultiplied)
        float ax = (float)hs[0], ay = (float)hs[1];
        float az = (float)hs[2], aw = (float)hs[3];
        const int* eb = &sle[li * CAP];
        int j = 0;
        for (; j + 4 <= e1; j += 4) {
            int s0 = eb[j], s1 = eb[j + 1], s2 = eb[j + 2], s3 = eb[j + 3];
            half4v a0 = xh4[s0 * 24 + lane], a1 = xh4[s1 * 24 + lane];
            half4v a2 = xh4[s2 * 24 + lane], a3 = xh4[s3 * 24 + lane];
            ax += (float)a0[0] + (float)a1[0] + (float)a2[0] + (float)a3[0];
            ay += (float)a0[1] + (float)a1[1] + (float)a2[1] + (float)a3[1];
            az += (float)a0[2] + (float)a1[2] + (float)a2[2] + (float)a3[2];
            aw += (float)a0[3] + (float)a1[3] + (float)a2[3] + (float)a3[3];
        }
        for (; j < e1; ++j) {
            int s = eb[j];
            half4v a = xh4[s * 24 + lane];
            ax += (float)a[0]; ay += (float)a[1]; az += (float)a[2]; aw += (float)a[3];
        }
        float4 o;
        o.x = dd * ax; o.y = dd * ay; o.z = dd * az; o.w = dd * aw;
        sx4[li * 24 + lane] = o;
    }
    __syncthreads();

    // per-(node, h) compute with folded weights; h = lane
    int h = lane;
    float rMz[FDIM], rMh[FDIM];
#pragma unroll
    for (int f = 0; f < FDIM; ++f) {
        rMz[f] = Mz[f * HDIM + h];
        rMh[f] = Mh[f * HDIM + h];
    }
    float u[PDIM], v[PDIM];
    float c0 = cz[h], c1 = ch[h];
#pragma unroll
    for (int t = 0; t < PDIM; ++t) { u[t] = c0; v[t] = c1; }

    const float* sxf = reinterpret_cast<const float*>(&sx4[li * 24]);
#pragma unroll
    for (int f = 0; f < FDIM; ++f) {
        const float4 a = *reinterpret_cast<const float4*>(sxf + f * PDIM);
        const float4 b = *reinterpret_cast<const float4*>(sxf + f * PDIM + 4);
        const float4 c = *reinterpret_cast<const float4*>(sxf + f * PDIM + 8);
        float mz = rMz[f], mh = rMh[f];
        u[0] += a.x * mz; u[1]  += a.y * mz; u[2]  += a.z * mz; u[3]  += a.w * mz;
        u[4] += b.x * mz; u[5]  += b.y * mz; u[6]  += b.z * mz; u[7]  += b.w * mz;
        u[8] += c.x * mz; u[9]  += c.y * mz; u[10] += c.z * mz; u[11] += c.w * mz;
        v[0] += a.x * mh; v[1]  += a.y * mh; v[2]  += a.z * mh; v[3]  += a.w * mh;
        v[4] += b.x * mh; v[5]  += b.y * mh; v[6]  += b.z * mh; v[7]  += b.w * mh;
        v[8] += c.x * mh; v[9]  += c.y * mh; v[10] += c.z * mh; v[11] += c.w * mh;
    }

    float accum = 0.f;
#pragma unroll
    for (int t = 0; t < PDIM; ++t) {
        float omz = 1.f / (1.f + __expf(u[t]));             // 1 - sigmoid(u)
        float th  = 1.f - 2.f / (__expf(2.f * v[t]) + 1.f); // tanh(v), overflow-safe
        accum += sprobs[t] * omz * th;
    }
    sh[li][h] = fmaxf(accum, 0.f);
    __builtin_amdgcn_wave_barrier();   // producers/consumers share the wave

    if (h < PDIM) {
        float o = linb[h];
#pragma unroll
        for (int k = 0; k < HDIM; ++k) o += sh[li][k] * linW[k * PDIM + h];
        out[(size_t)node * PDIM + h] = o;
    }
}

static inline size_t al256(size_t x) { return (x + 255) & ~(size_t)255; }

extern "C" void kernel_launch(void* const* d_in, const int* in_sizes, int n_in,
                              void* d_out, int out_size, void* d_ws, size_t ws_size,
                              hipStream_t stream) {
    const float* x    = (const float*)d_in[0];
    const int*   ei   = (const int*)d_in[1];
    const float* Wz   = (const float*)d_in[2];
    const float* bz   = (const float*)d_in[3];
    // d_in[4..5] (W_r, b_r) dead: H=0 kills the R gate
    const float* Wh   = (const float*)d_in[6];
    const float* bh   = (const float*)d_in[7];
    const float* Lz   = (const float*)d_in[8];
    const float* lbz  = (const float*)d_in[9];
    // d_in[10..11] (L_r, lb_r) dead
    const float* Lh   = (const float*)d_in[12];
    const float* lbh  = (const float*)d_in[13];
    const float* att  = (const float*)d_in[14];
    const float* linW = (const float*)d_in[15];
    const float* linb = (const float*)d_in[16];
    float* out = (float*)d_out;

    const int* src = ei;
    const int* dst = ei + NE;

    char* w = (char*)d_ws;
    size_t o = 0;
    int*      cursor = (int*)(w + o);      o += al256((size_t)NN * CSTR * 4);  // 1.28 MB
    int*      ebuf   = (int*)(w + o);      o += al256((size_t)NN * CAP * 4);   // 6.4 MB
    _Float16* xh     = (_Float16*)(w + o); o += al256((size_t)NN * FP * 2);    // 3.84 MB
    float*    Mz     = (float*)(w + o);    o += al256((size_t)FDIM * HDIM * 4);
    float*    Mh     = (float*)(w + o);    o += al256((size_t)FDIM * HDIM * 4);
    float*    czp    = (float*)(w + o);    o += al256((size_t)HDIM * 4);
    float*    chp    = (float*)(w + o);    o += al256((size_t)HDIM * 4);
    float*    probs  = (float*)(w + o);    o += al256((size_t)PDIM * 4);

    const int B = 256;
    k_prep<<<(NN * CSTR / 4 + B - 1) / B, B, 0, stream>>>(cursor,
                                                          Wz, bz, Wh, bh,
                                                          Lz, lbz, Lh, lbh, att,
                                                          Mz, Mh, czp, chp, probs);
    k_bucket<<<NE / 2 / B, B, 0, stream>>>(src, dst, cursor, ebuf);
    k_xh<<<(NN * (FP / 8) + B - 1) / B, B, 0, stream>>>(x, cursor, (half8v*)xh);
    k_gnode<<<NN / 8, B, 0, stream>>>(xh, cursor, ebuf,
                                      Mz, Mh, czp, chp, probs, linW, linb, out);
}